// Round 13
// baseline (254.796 us; speedup 1.0000x reference)
//
#include <hip/hip_runtime.h>
#include <hip/hip_bf16.h>
#include <cmath>

// Problem constants
constexpr int B  = 4;
constexpr int T  = 2048;
constexpr int C  = 768;
constexpr int H  = 12;
constexpr int Dh = 64;
constexpr int M  = B * T;          // 8192
constexpr int NQKV = 3 * C;        // 2304 fused QKV output width
constexpr int WS2  = C * C;        // 589824 elems per weight matrix

typedef short bf16x8 __attribute__((ext_vector_type(8)));
typedef short bf16x4 __attribute__((ext_vector_type(4)));
typedef float f32x4  __attribute__((ext_vector_type(4)));
typedef float f32x16 __attribute__((ext_vector_type(16)));

// softmax scale folded into Q at GEMM epilogue: (1/sqrt(Dh)) * log2(e)
constexpr float SOFT_SCALE = 0.18033688011112042f;

__device__ inline short f2bf(float f) {   // fp32 -> bf16 round-nearest-even
    unsigned u = __float_as_uint(f);
    u += 0x7fffu + ((u >> 16) & 1u);
    return (short)(u >> 16);
}

__device__ inline unsigned pk_bf16(float a, float b) {  // packed pair (RNE)
    __hip_bfloat162 h = __float22bfloat162_rn(float2{a, b});
    return *(unsigned*)&h;
}

__device__ inline bf16x8 mk8(unsigned a, unsigned b, unsigned c, unsigned d) {
    union { unsigned u[4]; bf16x8 v; } x;
    x.u[0] = a; x.u[1] = b; x.u[2] = c; x.u[3] = d;
    return x.v;
}

// global(AS1) -> LDS(AS3) 16-byte async copy; HW writes ldsbase + lane*16.
typedef const __attribute__((address_space(1))) unsigned GU;
typedef __attribute__((address_space(3))) unsigned LU;
__device__ inline void async_copy16(const void* g, void* l) {
    __builtin_amdgcn_global_load_lds((GU*)g, (LU*)l, 16, 0, 0);
}

// ---------------------------------------------------------------------------
// Fused fp32 -> bf16 convert for x + all four weights (one launch).
// ---------------------------------------------------------------------------
constexpr size_t XE = (size_t)M * C;                // 6291456
constexpr size_t CV_TOTAL = XE + 4 * (size_t)WS2;   // 8650752

__global__ __launch_bounds__(256)
void convert_all(const float* __restrict__ x,  const float* __restrict__ Wq,
                 const float* __restrict__ Wk, const float* __restrict__ Wv,
                 const float* __restrict__ Wp,
                 short* __restrict__ xb, short* __restrict__ Wqkv,
                 short* __restrict__ Wpb) {
    size_t i = ((size_t)blockIdx.x * 256 + threadIdx.x) * 4;
    const float* src; short* dst; size_t off;
    if (i < XE)                        { src = x;  dst = xb;            off = i; }
    else if (i < XE + WS2)             { src = Wq; dst = Wqkv;          off = i - XE; }
    else if (i < XE + 2 * (size_t)WS2) { src = Wk; dst = Wqkv + WS2;    off = i - XE - WS2; }
    else if (i < XE + 3 * (size_t)WS2) { src = Wv; dst = Wqkv + 2 * WS2; off = i - XE - 2 * (size_t)WS2; }
    else                               { src = Wp; dst = Wpb;           off = i - XE - 3 * (size_t)WS2; }
    float4 v = *(const float4*)(src + off);
    bf16x4 o; o[0] = f2bf(v.x); o[1] = f2bf(v.y); o[2] = f2bf(v.z); o[3] = f2bf(v.w);
    *(bf16x4*)(dst + off) = o;
}

// ---------------------------------------------------------------------------
// bf16 MFMA GEMM (128-tile, r8-verified): QKV + projection.
// r12's 256^2 2-phase lost to this structure's multi-block TLP (240.8 vs
// 232.3) -> GEMMs frozen on this form. XCD-slab swizzle (r6, +4.7 us).
// ---------------------------------------------------------------------------
constexpr int BM = 128;
constexpr int MTILES = M / BM;       // 64

template<int BN_, int WMW, int WNW, int OUT_BF16, int QSCALE>
__global__ __launch_bounds__(256)
void gemm_bt(const short* __restrict__ A, const short* __restrict__ W,
             const float* __restrict__ bias0, const float* __restrict__ bias1,
             const float* __restrict__ bias2,
             void* __restrict__ Yv, int Ndim, int Kdim) {
    constexpr int MT  = BM / WMW / 16;
    constexpr int NT  = BN_ / WNW / 16;
    constexpr int NCH = (BM + BN_) / 16;     // 16-row chunks per k-half

    __shared__ short As[2][BM * 32];
    __shared__ short Bs[2][BN_ * 32];

    const int tid  = threadIdx.x;
    const int wave = tid >> 6;
    const int lane = tid & 63;
    const int li   = lane & 15;
    const int quad = lane >> 4;
    const int wm   = wave % WMW;
    const int wn   = wave / WMW;

    // XCD-slab block swizzle
    const int ntiles = Ndim / BN_;
    const int bid  = blockIdx.x;
    const int xcd  = bid & 7;
    const int idx  = bid >> 3;
    const int mloc = idx / ntiles;           // 0 .. MTILES/8-1
    const int ntt  = idx % ntiles;
    const int m0   = (xcd * (MTILES / 8) + mloc) * BM;
    const int n0   = ntt * BN_;

    f32x4 acc[MT][NT];
    #pragma unroll
    for (int i = 0; i < MT; ++i)
        #pragma unroll
        for (int j = 0; j < NT; ++j)
            acc[i][j] = (f32x4){0.f, 0.f, 0.f, 0.f};

    const int lrow = lane >> 2;          // 0..15 row within 16-row chunk
    const int lkof = (lane & 3) * 8;     // 16B chunk within 32-short half-row

    for (int k0 = 0; k0 < Kdim; k0 += 64) {
        __syncthreads();
        #pragma unroll
        for (int h = 0; h < 2; ++h)
            #pragma unroll
            for (int ii = 0; ii < NCH / 4; ++ii) {
                int c = ii * 4 + wave;
                if (c < BM / 16)
                    async_copy16(A + (size_t)(m0 + c * 16 + lrow) * Kdim
                                   + k0 + h * 32 + lkof,
                                 &As[h][c * 512]);
                else
                    async_copy16(W + (size_t)(n0 + (c - BM / 16) * 16 + lrow) * Kdim
                                   + k0 + h * 32 + lkof,
                                 &Bs[h][(c - BM / 16) * 512]);
            }
        __syncthreads();

        #pragma unroll
        for (int h = 0; h < 2; ++h) {
            bf16x8 af[MT], bfr[NT];
            #pragma unroll
            for (int t = 0; t < MT; ++t)
                af[t] = *(const bf16x8*)&As[h][(wm * MT * 16 + t * 16 + li) * 32 + quad * 8];
            #pragma unroll
            for (int t = 0; t < NT; ++t)
                bfr[t] = *(const bf16x8*)&Bs[h][(wn * NT * 16 + t * 16 + li) * 32 + quad * 8];
            #pragma unroll
            for (int i = 0; i < MT; ++i)
                #pragma unroll
                for (int j = 0; j < NT; ++j)
                    acc[i][j] = __builtin_amdgcn_mfma_f32_16x16x32_bf16(
                        af[i], bfr[j], acc[i][j], 0, 0, 0);
        }
    }

    float bb[NT];
    #pragma unroll
    for (int nt = 0; nt < NT; ++nt) bb[nt] = 0.f;
    if (bias0) {
        int s = n0 / C;
        const float* bp = (s == 0) ? bias0 : ((s == 1) ? bias1 : bias2);
        int nb = n0 % C;
        #pragma unroll
        for (int nt = 0; nt < NT; ++nt)
            bb[nt] = bp[nb + wn * NT * 16 + nt * 16 + li];
    }

    #pragma unroll
    for (int mt = 0; mt < MT; ++mt)
        #pragma unroll
        for (int nt = 0; nt < NT; ++nt)
            #pragma unroll
            for (int r = 0; r < 4; ++r) {
                int row = m0 + wm * MT * 16 + mt * 16 + quad * 4 + r;
                int col = n0 + wn * NT * 16 + nt * 16 + li;
                float v = acc[mt][nt][r] + bb[nt];
                if constexpr (QSCALE) {
                    if (n0 < C) v *= SOFT_SCALE;   // wave-uniform branch
                }
                if constexpr (OUT_BF16)
                    ((short*)Yv)[(size_t)row * Ndim + col] = f2bf(v);
                else
                    ((float*)Yv)[(size_t)row * Ndim + col] = v;
            }
}

// ---------------------------------------------------------------------------
// MFMA flash attention, 32x32x16, in-register softmax.
// r13: 64 q-rows PER WAVE (was 32). 128-thread blocks (2 waves), grid 768
// unchanged (3 blocks/CU, LDS 108 KB). Per-tile overhead (barrier, staging
// issue, addressing) is amortized over 2x work; staging bytes per unit work
// halve. Per-qg sequential compute keeps st live at 32 regs; total live
// ~222 < 256 (__launch_bounds__(128,2)). Numerics and LDS layout identical
// to the r11-verified kernel. Tests the amortization side of the plateau
// (r4 tested the TLP side: more waves = no gain).
// ---------------------------------------------------------------------------
constexpr int QT   = 128;
constexpr int KTT  = 64;
constexpr int LSTR = 72;
constexpr int QS   = NQKV;

__global__ __launch_bounds__(128, 2)
void attn_fwd(const short* __restrict__ QKV, short* __restrict__ O) {
    __shared__ short Ks0[KTT * LSTR];
    __shared__ short Ks1[KTT * LSTR];
    __shared__ short Vt0[Dh * LSTR];
    __shared__ short Vt1[Dh * LSTR];

    const int tid  = threadIdx.x;        // 0..127
    const int wave = tid >> 6;           // 0..1
    const int lane = tid & 63;
    const int r31  = lane & 31;
    const int hi   = lane >> 5;

    // XCD grouping: 768 = 8 * 6 * 16, bijective (r10, verified)
    const int bid   = blockIdx.x;
    const int xcd   = bid & 7;
    const int idx   = bid >> 3;          // 0..95
    const int gloc  = idx >> 4;          // 0..5  (b,h)-group within XCD
    const int qt    = idx & 15;          // 0..15 q-tile
    const int group = xcd * 6 + gloc;    // 0..47
    const int b     = group / H;
    const int h     = group % H;
    const int qw    = qt * QT + wave * 64;   // 64 q-rows per wave

    const short* Qg = QKV + (size_t)(b * T) * QS + h * Dh;
    const short* Kg = QKV + (size_t)(b * T) * QS + C + h * Dh;
    const short* Vg = QKV + (size_t)(b * T) * QS + 2 * C + h * Dh;

    // Q B-fragments for both 32-row q-groups
    bf16x8 qf[2][4];
    #pragma unroll
    for (int qg = 0; qg < 2; ++qg)
        #pragma unroll
        for (int f = 0; f < 4; ++f)
            qf[qg][f] = *(const bf16x8*)(Qg + (size_t)(qw + qg * 32 + r31) * QS
                                            + f * 16 + hi * 8);

    bf16x8 ones;
    #pragma unroll
    for (int i = 0; i < 8; ++i) ones[i] = (short)0x3F80;

    f32x16 oacc0[2], oacc1[2], lacc[2];
    #pragma unroll
    for (int qg = 0; qg < 2; ++qg) {
        oacc0[qg] = (f32x16)(0.f);
        oacc1[qg] = (f32x16)(0.f);
        lacc[qg]  = (f32x16)(0.f);
    }

    // staging roles (128 threads): K 64x64 shorts, V^T 64x64 shorts
    const int ktok = tid >> 3;           // 0..15 (4 rows each, stride 16)
    const int kch  = tid & 7;
    const int vd2  = (tid & 31) * 2;     // d-pair
    const int vg   = tid >> 5;           // 0..3 (16 tokens each)

    int4 kpre[4];
    unsigned vpre[16];

    auto load_regs = [&](int kt0) {
        #pragma unroll
        for (int r = 0; r < 4; ++r)
            kpre[r] = *(const int4*)(Kg + (size_t)(kt0 + ktok + r * 16) * QS + kch * 8);
        #pragma unroll
        for (int t2 = 0; t2 < 16; ++t2)
            vpre[t2] = *(const unsigned*)(Vg + (size_t)(kt0 + vg * 16 + t2) * QS + vd2);
    };
    auto write_tile = [&](short (&KsT)[KTT * LSTR], short (&VtT)[Dh * LSTR]) {
        #pragma unroll
        for (int r = 0; r < 4; ++r)
            *(int4*)&KsT[(ktok + r * 16) * LSTR + kch * 8] = kpre[r];
        unsigned lo[8], hh[8];
        #pragma unroll
        for (int j = 0; j < 8; ++j) {
            lo[j] = __builtin_amdgcn_perm(vpre[2 * j + 1], vpre[2 * j], 0x05040100u);
            hh[j] = __builtin_amdgcn_perm(vpre[2 * j + 1], vpre[2 * j], 0x07060302u);
        }
        *(int4*)&VtT[vd2 * LSTR + vg * 16]           = make_int4(lo[0], lo[1], lo[2], lo[3]);
        *(int4*)&VtT[vd2 * LSTR + vg * 16 + 8]       = make_int4(lo[4], lo[5], lo[6], lo[7]);
        *(int4*)&VtT[(vd2 + 1) * LSTR + vg * 16]     = make_int4(hh[0], hh[1], hh[2], hh[3]);
        *(int4*)&VtT[(vd2 + 1) * LSTR + vg * 16 + 8] = make_int4(hh[4], hh[5], hh[6], hh[7]);
    };

    // One half-iteration: compute tile in (KsT,VtT) for BOTH q-groups;
    // stage the next tile (in kpre/vpre) into (KsN,VtN) after qg0's QK.
    auto half_iter = [&](const short (&KsT)[KTT * LSTR], const short (&VtT)[Dh * LSTR],
                         short (&KsN)[KTT * LSTR], short (&VtN)[Dh * LSTR],
                         bool do_stage, int next_load) {
        __syncthreads();

        #pragma unroll
        for (int qg = 0; qg < 2; ++qg) {
            // ---- QK^T for this q-group ----
            f32x16 st0 = (f32x16)(0.f);
            f32x16 st1 = (f32x16)(0.f);
            __builtin_amdgcn_s_setprio(1);
            #pragma unroll
            for (int f = 0; f < 4; ++f) {
                bf16x8 k0 = *(const bf16x8*)&KsT[(r31)      * LSTR + f * 16 + hi * 8];
                bf16x8 k1 = *(const bf16x8*)&KsT[(32 + r31) * LSTR + f * 16 + hi * 8];
                st0 = __builtin_amdgcn_mfma_f32_32x32x16_bf16(k0, qf[qg][f], st0, 0, 0, 0);
                st1 = __builtin_amdgcn_mfma_f32_32x32x16_bf16(k1, qf[qg][f], st1, 0, 0, 0);
            }
            __builtin_amdgcn_s_setprio(0);

            // staging fills qg0's MFMA/softmax shadow
            if (qg == 0) {
                if (do_stage)       write_tile(KsN, VtN);
                if (next_load >= 0) load_regs(next_load);
            }

            // ---- per 32-token k-block: exp2 -> bf16 frags -> PV ----
            #pragma unroll
            for (int kb = 0; kb < 2; ++kb) {
                f32x16 s = kb ? st1 : st0;
                unsigned d[8];
                #pragma unroll
                for (int j = 0; j < 8; ++j) {
                    float pa = __builtin_amdgcn_exp2f(s[2 * j]);
                    float pb = __builtin_amdgcn_exp2f(s[2 * j + 1]);
                    d[j] = pk_bf16(pa, pb);
                }
                auto s02 = __builtin_amdgcn_permlane32_swap(d[0], d[2], false, false);
                auto s13 = __builtin_amdgcn_permlane32_swap(d[1], d[3], false, false);
                auto s46 = __builtin_amdgcn_permlane32_swap(d[4], d[6], false, false);
                auto s57 = __builtin_amdgcn_permlane32_swap(d[5], d[7], false, false);
                bf16x8 pf0 = mk8(s02[0], s13[0], s02[1], s13[1]);  // k = kb*32 + 0..15
                bf16x8 pf1 = mk8(s46[0], s57[0], s46[1], s57[1]);  // k = kb*32 + 16..31

                __builtin_amdgcn_s_setprio(1);
                lacc[qg] = __builtin_amdgcn_mfma_f32_32x32x16_bf16(pf0, ones, lacc[qg], 0, 0, 0);
                lacc[qg] = __builtin_amdgcn_mfma_f32_32x32x16_bf16(pf1, ones, lacc[qg], 0, 0, 0);

                bf16x8 v00 = *(const bf16x8*)&VtT[(r31)      * LSTR + kb * 32 + hi * 8];
                bf16x8 v01 = *(const bf16x8*)&VtT[(r31)      * LSTR + kb * 32 + 16 + hi * 8];
                bf16x8 v10 = *(const bf16x8*)&VtT[(32 + r31) * LSTR + kb * 32 + hi * 8];
                bf16x8 v11 = *(const bf16x8*)&VtT[(32 + r31) * LSTR + kb * 32 + 16 + hi * 8];
                oacc0[qg] = __builtin_amdgcn_mfma_f32_32x32x16_bf16(pf0, v00, oacc0[qg], 0, 0, 0);
                oacc0[qg] = __builtin_amdgcn_mfma_f32_32x32x16_bf16(pf1, v01, oacc0[qg], 0, 0, 0);
                oacc1[qg] = __builtin_amdgcn_mfma_f32_32x32x16_bf16(pf0, v10, oacc1[qg], 0, 0, 0);
                oacc1[qg] = __builtin_amdgcn_mfma_f32_32x32x16_bf16(pf1, v11, oacc1[qg], 0, 0, 0);
                __builtin_amdgcn_s_setprio(0);
            }
        }
    };

    // prologue: tile 0 -> buf0 (visible after first barrier); tile 1 -> regs
    load_regs(0);
    write_tile(Ks0, Vt0);
    load_regs(KTT);

    for (int kt = 0; kt < T; kt += 2 * KTT) {
        half_iter(Ks0, Vt0, Ks1, Vt1, true,
                  (kt + 2 * KTT < T) ? kt + 2 * KTT : -1);
        half_iter(Ks1, Vt1, Ks0, Vt0, kt + 2 * KTT < T,
                  (kt + 3 * KTT < T) ? kt + 3 * KTT : -1);
    }

    // epilogue: O[q][d]; reg r -> q-row (r&3) + 8*(r>>2) + 4*hi per q-group
    #pragma unroll
    for (int qg = 0; qg < 2; ++qg)
        #pragma unroll
        for (int r = 0; r < 16; ++r) {
            float inv = 1.0f / lacc[qg][r];
            int row = (r & 3) + 8 * (r >> 2) + 4 * hi;
            short* op = O + (size_t)(b * T + qw + qg * 32 + row) * C + h * Dh + r31;
            op[0]  = f2bf(oacc0[qg][r] * inv);
            op[32] = f2bf(oacc1[qg][r] * inv);
        }
}

// ---------------------------------------------------------------------------
// Launch
// ---------------------------------------------------------------------------
extern "C" void kernel_launch(void* const* d_in, const int* in_sizes, int n_in,
                              void* d_out, int out_size, void* d_ws, size_t ws_size,
                              hipStream_t stream) {
    (void)in_sizes; (void)n_in; (void)out_size; (void)ws_size;

    const float* x  = (const float*)d_in[0];
    const float* Wq = (const float*)d_in[1];
    const float* bq = (const float*)d_in[2];
    const float* Wk = (const float*)d_in[3];
    const float* bk = (const float*)d_in[4];
    const float* Wv = (const float*)d_in[5];
    const float* bv = (const float*)d_in[6];
    const float* Wp = (const float*)d_in[7];
    float* out = (float*)d_out;

    short* xb    = (short*)d_ws;                 // [M][C]      bf16
    short* Wqkv  = xb + (size_t)M * C;           // [2304][768] bf16
    short* Wpb   = Wqkv + 3 * (size_t)WS2;       // [768][768]  bf16
    short* QKVb  = Wpb + (size_t)WS2;            // [M][2304]   bf16 (Q pre-scaled)
    short* AOb   = QKVb + (size_t)M * NQKV;      // [M][C]      bf16

    convert_all<<<dim3(CV_TOTAL / 1024), 256, 0, stream>>>(
        x, Wq, Wk, Wv, Wp, xb, Wqkv, Wpb);

    // Fused QKV projection: [8192 x 2304], 128^2 tiles (r11-verified).
    gemm_bt<128, 2, 2, 1, 1><<<dim3(MTILES * (NQKV / 128)), 256, 0, stream>>>(
        xb, Wqkv, bq, bk, bv, QKVb, NQKV, C);

    // attn: 1-D grid 768, XCD-grouped; 128-thread blocks, 64 q-rows/wave
    attn_fwd<<<dim3((T / QT) * H * B), 128, 0, stream>>>(QKVb, AOb);

    // Output projection: [8192 x 768] fp32 out, BN=64 (r6-verified best).
    gemm_bt<64, 4, 1, 0, 0><<<dim3(MTILES * (C / 64)), 256, 0, stream>>>(
        AOb, Wpb, nullptr, nullptr, nullptr, out, C, C);
}

// Round 14
// 232.331 us; speedup vs baseline: 1.0967x; 1.0967x over previous
//
#include <hip/hip_runtime.h>
#include <hip/hip_bf16.h>
#include <cmath>

// Problem constants
constexpr int B  = 4;
constexpr int T  = 2048;
constexpr int C  = 768;
constexpr int H  = 12;
constexpr int Dh = 64;
constexpr int M  = B * T;          // 8192
constexpr int NQKV = 3 * C;        // 2304 fused QKV output width
constexpr int WS2  = C * C;        // 589824 elems per weight matrix

typedef short bf16x8 __attribute__((ext_vector_type(8)));
typedef short bf16x4 __attribute__((ext_vector_type(4)));
typedef float f32x4  __attribute__((ext_vector_type(4)));
typedef float f32x16 __attribute__((ext_vector_type(16)));

// softmax scale folded into Q at GEMM epilogue: (1/sqrt(Dh)) * log2(e)
constexpr float SOFT_SCALE = 0.18033688011112042f;

__device__ inline short f2bf(float f) {   // fp32 -> bf16 round-nearest-even
    unsigned u = __float_as_uint(f);
    u += 0x7fffu + ((u >> 16) & 1u);
    return (short)(u >> 16);
}

__device__ inline unsigned pk_bf16(float a, float b) {  // packed pair (RNE)
    __hip_bfloat162 h = __float22bfloat162_rn(float2{a, b});
    return *(unsigned*)&h;
}

__device__ inline bf16x8 mk8(unsigned a, unsigned b, unsigned c, unsigned d) {
    union { unsigned u[4]; bf16x8 v; } x;
    x.u[0] = a; x.u[1] = b; x.u[2] = c; x.u[3] = d;
    return x.v;
}

// global(AS1) -> LDS(AS3) 16-byte async copy; HW writes ldsbase + lane*16.
typedef const __attribute__((address_space(1))) unsigned GU;
typedef __attribute__((address_space(3))) unsigned LU;
__device__ inline void async_copy16(const void* g, void* l) {
    __builtin_amdgcn_global_load_lds((GU*)g, (LU*)l, 16, 0, 0);
}

// ---------------------------------------------------------------------------
// Fused fp32 -> bf16 convert for x + all four weights (one launch).
// ---------------------------------------------------------------------------
constexpr size_t XE = (size_t)M * C;                // 6291456
constexpr size_t CV_TOTAL = XE + 4 * (size_t)WS2;   // 8650752

__global__ __launch_bounds__(256)
void convert_all(const float* __restrict__ x,  const float* __restrict__ Wq,
                 const float* __restrict__ Wk, const float* __restrict__ Wv,
                 const float* __restrict__ Wp,
                 short* __restrict__ xb, short* __restrict__ Wqkv,
                 short* __restrict__ Wpb) {
    size_t i = ((size_t)blockIdx.x * 256 + threadIdx.x) * 4;
    const float* src; short* dst; size_t off;
    if (i < XE)                        { src = x;  dst = xb;            off = i; }
    else if (i < XE + WS2)             { src = Wq; dst = Wqkv;          off = i - XE; }
    else if (i < XE + 2 * (size_t)WS2) { src = Wk; dst = Wqkv + WS2;    off = i - XE - WS2; }
    else if (i < XE + 3 * (size_t)WS2) { src = Wv; dst = Wqkv + 2 * WS2; off = i - XE - 2 * (size_t)WS2; }
    else                               { src = Wp; dst = Wpb;           off = i - XE - 3 * (size_t)WS2; }
    float4 v = *(const float4*)(src + off);
    bf16x4 o; o[0] = f2bf(v.x); o[1] = f2bf(v.y); o[2] = f2bf(v.z); o[3] = f2bf(v.w);
    *(bf16x4*)(dst + off) = o;
}

// ---------------------------------------------------------------------------
// bf16 MFMA GEMM (128-tile, r8-verified): QKV + projection.
// Frozen: r9 (BK=32 dbuf) and r12 (256^2 2-phase) both regressed vs this
// structure's multi-block TLP at K=768. XCD-slab swizzle (r6, +4.7 us).
// ---------------------------------------------------------------------------
constexpr int BM = 128;
constexpr int MTILES = M / BM;       // 64

template<int BN_, int WMW, int WNW, int OUT_BF16, int QSCALE>
__global__ __launch_bounds__(256)
void gemm_bt(const short* __restrict__ A, const short* __restrict__ W,
             const float* __restrict__ bias0, const float* __restrict__ bias1,
             const float* __restrict__ bias2,
             void* __restrict__ Yv, int Ndim, int Kdim) {
    constexpr int MT  = BM / WMW / 16;
    constexpr int NT  = BN_ / WNW / 16;
    constexpr int NCH = (BM + BN_) / 16;     // 16-row chunks per k-half

    __shared__ short As[2][BM * 32];
    __shared__ short Bs[2][BN_ * 32];

    const int tid  = threadIdx.x;
    const int wave = tid >> 6;
    const int lane = tid & 63;
    const int li   = lane & 15;
    const int quad = lane >> 4;
    const int wm   = wave % WMW;
    const int wn   = wave / WMW;

    // XCD-slab block swizzle
    const int ntiles = Ndim / BN_;
    const int bid  = blockIdx.x;
    const int xcd  = bid & 7;
    const int idx  = bid >> 3;
    const int mloc = idx / ntiles;           // 0 .. MTILES/8-1
    const int ntt  = idx % ntiles;
    const int m0   = (xcd * (MTILES / 8) + mloc) * BM;
    const int n0   = ntt * BN_;

    f32x4 acc[MT][NT];
    #pragma unroll
    for (int i = 0; i < MT; ++i)
        #pragma unroll
        for (int j = 0; j < NT; ++j)
            acc[i][j] = (f32x4){0.f, 0.f, 0.f, 0.f};

    const int lrow = lane >> 2;          // 0..15 row within 16-row chunk
    const int lkof = (lane & 3) * 8;     // 16B chunk within 32-short half-row

    for (int k0 = 0; k0 < Kdim; k0 += 64) {
        __syncthreads();
        #pragma unroll
        for (int h = 0; h < 2; ++h)
            #pragma unroll
            for (int ii = 0; ii < NCH / 4; ++ii) {
                int c = ii * 4 + wave;
                if (c < BM / 16)
                    async_copy16(A + (size_t)(m0 + c * 16 + lrow) * Kdim
                                   + k0 + h * 32 + lkof,
                                 &As[h][c * 512]);
                else
                    async_copy16(W + (size_t)(n0 + (c - BM / 16) * 16 + lrow) * Kdim
                                   + k0 + h * 32 + lkof,
                                 &Bs[h][(c - BM / 16) * 512]);
            }
        __syncthreads();

        #pragma unroll
        for (int h = 0; h < 2; ++h) {
            bf16x8 af[MT], bfr[NT];
            #pragma unroll
            for (int t = 0; t < MT; ++t)
                af[t] = *(const bf16x8*)&As[h][(wm * MT * 16 + t * 16 + li) * 32 + quad * 8];
            #pragma unroll
            for (int t = 0; t < NT; ++t)
                bfr[t] = *(const bf16x8*)&Bs[h][(wn * NT * 16 + t * 16 + li) * 32 + quad * 8];
            #pragma unroll
            for (int i = 0; i < MT; ++i)
                #pragma unroll
                for (int j = 0; j < NT; ++j)
                    acc[i][j] = __builtin_amdgcn_mfma_f32_16x16x32_bf16(
                        af[i], bfr[j], acc[i][j], 0, 0, 0);
        }
    }

    float bb[NT];
    #pragma unroll
    for (int nt = 0; nt < NT; ++nt) bb[nt] = 0.f;
    if (bias0) {
        int s = n0 / C;
        const float* bp = (s == 0) ? bias0 : ((s == 1) ? bias1 : bias2);
        int nb = n0 % C;
        #pragma unroll
        for (int nt = 0; nt < NT; ++nt)
            bb[nt] = bp[nb + wn * NT * 16 + nt * 16 + li];
    }

    #pragma unroll
    for (int mt = 0; mt < MT; ++mt)
        #pragma unroll
        for (int nt = 0; nt < NT; ++nt)
            #pragma unroll
            for (int r = 0; r < 4; ++r) {
                int row = m0 + wm * MT * 16 + mt * 16 + quad * 4 + r;
                int col = n0 + wn * NT * 16 + nt * 16 + li;
                float v = acc[mt][nt][r] + bb[nt];
                if constexpr (QSCALE) {
                    if (n0 < C) v *= SOFT_SCALE;   // wave-uniform branch
                }
                if constexpr (OUT_BF16)
                    ((short*)Yv)[(size_t)row * Ndim + col] = f2bf(v);
                else
                    ((float*)Yv)[(size_t)row * Ndim + col] = v;
            }
}

// ---------------------------------------------------------------------------
// MFMA flash attention, 32x32x16, in-register softmax, static double-buffer
// (r11, verified 90.6 us) + XCD grouping (r10, FETCH 107.5 -> 21.5 MB).
// FROZEN — plateau confirmed from both directions:
//   r4  split-K occupancy 12->16 waves/CU: no gain
//   r5  barrier amortization (+prefetch regs): spill, -6x
//   r8  LDS dbuf (1 barrier/tile): -1.7 us
//   r10 XCD grouping (L2-resident K/V): traffic 5x down, time flat
//   r11 static dbuf naming (alias-exact): -2.2 us
//   r13 64 q-rows/wave (2x amortization, 1.5 waves/SIMD): -30%
// ~90 us = the per-tile [QK -> softmax -> PV] dependency chain at 3
// blocks/CU; breaking it needs a co-designed multi-phase rebuild.
// ---------------------------------------------------------------------------
constexpr int QT   = 128;
constexpr int KTT  = 64;
constexpr int LSTR = 72;
constexpr int QS   = NQKV;

__global__ __launch_bounds__(256, 3)
void attn_fwd(const short* __restrict__ QKV, short* __restrict__ O) {
    __shared__ short Ks0[KTT * LSTR];
    __shared__ short Ks1[KTT * LSTR];
    __shared__ short Vt0[Dh * LSTR];
    __shared__ short Vt1[Dh * LSTR];

    const int tid  = threadIdx.x;
    const int wave = tid >> 6;
    const int lane = tid & 63;
    const int r31  = lane & 31;
    const int hi   = lane >> 5;

    // XCD grouping: 768 = 8 * 6 * 16, bijective (r10, verified)
    const int bid   = blockIdx.x;
    const int xcd   = bid & 7;
    const int idx   = bid >> 3;          // 0..95
    const int gloc  = idx >> 4;          // 0..5  (b,h)-group within XCD
    const int qt    = idx & 15;          // 0..15 q-tile
    const int group = xcd * 6 + gloc;    // 0..47
    const int b     = group / H;
    const int h     = group % H;
    const int qw    = qt * QT + wave * 32;

    const short* Qg = QKV + (size_t)(b * T) * QS + h * Dh;
    const short* Kg = QKV + (size_t)(b * T) * QS + C + h * Dh;
    const short* Vg = QKV + (size_t)(b * T) * QS + 2 * C + h * Dh;

    // Q B-fragments: lane holds Q[row = qw + (lane&31)][k = f*16 + hi*8 .. +7]
    bf16x8 qf[4];
    #pragma unroll
    for (int f = 0; f < 4; ++f)
        qf[f] = *(const bf16x8*)(Qg + (size_t)(qw + r31) * QS + f * 16 + hi * 8);

    bf16x8 ones;
    #pragma unroll
    for (int i = 0; i < 8; ++i) ones[i] = (short)0x3F80;

    f32x16 oacc0 = (f32x16)(0.f);
    f32x16 oacc1 = (f32x16)(0.f);
    f32x16 lacc  = (f32x16)(0.f);

    const int ktok = tid >> 3;
    const int kch  = tid & 7;
    const int vd2  = (tid & 31) * 2;
    const int vg   = tid >> 5;

    int4 kpre[2];
    unsigned vpre[8];

    auto load_regs = [&](int kt0) {
        kpre[0] = *(const int4*)(Kg + (size_t)(kt0 + ktok)      * QS + kch * 8);
        kpre[1] = *(const int4*)(Kg + (size_t)(kt0 + ktok + 32) * QS + kch * 8);
        #pragma unroll
        for (int t2 = 0; t2 < 8; ++t2)
            vpre[t2] = *(const unsigned*)(Vg + (size_t)(kt0 + vg * 8 + t2) * QS + vd2);
    };
    auto write_tile = [&](short (&KsT)[KTT * LSTR], short (&VtT)[Dh * LSTR]) {
        *(int4*)&KsT[ktok * LSTR + kch * 8]        = kpre[0];
        *(int4*)&KsT[(ktok + 32) * LSTR + kch * 8] = kpre[1];
        unsigned lo[4], hh[4];
        #pragma unroll
        for (int j = 0; j < 4; ++j) {
            lo[j] = __builtin_amdgcn_perm(vpre[2 * j + 1], vpre[2 * j], 0x05040100u);
            hh[j] = __builtin_amdgcn_perm(vpre[2 * j + 1], vpre[2 * j], 0x07060302u);
        }
        *(int4*)&VtT[vd2 * LSTR + vg * 8]       = make_int4(lo[0], lo[1], lo[2], lo[3]);
        *(int4*)&VtT[(vd2 + 1) * LSTR + vg * 8] = make_int4(hh[0], hh[1], hh[2], hh[3]);
    };

    // One half-iteration: compute tile in (KsT,VtT); optionally stage the
    // next tile (held in kpre/vpre) into (KsN,VtN) and prefetch tile+2.
    auto half_iter = [&](const short (&KsT)[KTT * LSTR], const short (&VtT)[Dh * LSTR],
                         short (&KsN)[KTT * LSTR], short (&VtN)[Dh * LSTR],
                         bool do_stage, int next_load) {
        __syncthreads();

        // ---- QK^T first: dependency chain starts at the barrier ----
        f32x16 st0 = (f32x16)(0.f);
        f32x16 st1 = (f32x16)(0.f);
        __builtin_amdgcn_s_setprio(1);
        #pragma unroll
        for (int f = 0; f < 4; ++f) {
            bf16x8 k0 = *(const bf16x8*)&KsT[(r31)      * LSTR + f * 16 + hi * 8];
            bf16x8 k1 = *(const bf16x8*)&KsT[(32 + r31) * LSTR + f * 16 + hi * 8];
            st0 = __builtin_amdgcn_mfma_f32_32x32x16_bf16(k0, qf[f], st0, 0, 0, 0);
            st1 = __builtin_amdgcn_mfma_f32_32x32x16_bf16(k1, qf[f], st1, 0, 0, 0);
        }
        __builtin_amdgcn_s_setprio(0);

        // ---- staging into the OTHER buffers: fills the MFMA shadow ----
        if (do_stage)       write_tile(KsN, VtN);
        if (next_load >= 0) load_regs(next_load);

        // ---- per 32-token k-block: exp2 -> bf16 frags (in reg) -> PV ----
        #pragma unroll
        for (int kb = 0; kb < 2; ++kb) {
            f32x16 s = kb ? st1 : st0;          // kb is unroll-constant
            unsigned d[8];
            #pragma unroll
            for (int j = 0; j < 8; ++j) {
                float pa = __builtin_amdgcn_exp2f(s[2 * j]);
                float pb = __builtin_amdgcn_exp2f(s[2 * j + 1]);
                d[j] = pk_bf16(pa, pb);
            }
            // redistribute across lane^32 partners
            auto s02 = __builtin_amdgcn_permlane32_swap(d[0], d[2], false, false);
            auto s13 = __builtin_amdgcn_permlane32_swap(d[1], d[3], false, false);
            auto s46 = __builtin_amdgcn_permlane32_swap(d[4], d[6], false, false);
            auto s57 = __builtin_amdgcn_permlane32_swap(d[5], d[7], false, false);
            bf16x8 pf0 = mk8(s02[0], s13[0], s02[1], s13[1]);  // k = kb*32 + 0..15
            bf16x8 pf1 = mk8(s46[0], s57[0], s46[1], s57[1]);  // k = kb*32 + 16..31

            __builtin_amdgcn_s_setprio(1);
            lacc = __builtin_amdgcn_mfma_f32_32x32x16_bf16(pf0, ones, lacc, 0, 0, 0);
            lacc = __builtin_amdgcn_mfma_f32_32x32x16_bf16(pf1, ones, lacc, 0, 0, 0);

            bf16x8 v00 = *(const bf16x8*)&VtT[(r31)      * LSTR + kb * 32 + hi * 8];
            bf16x8 v01 = *(const bf16x8*)&VtT[(r31)      * LSTR + kb * 32 + 16 + hi * 8];
            bf16x8 v10 = *(const bf16x8*)&VtT[(32 + r31) * LSTR + kb * 32 + hi * 8];
            bf16x8 v11 = *(const bf16x8*)&VtT[(32 + r31) * LSTR + kb * 32 + 16 + hi * 8];
            oacc0 = __builtin_amdgcn_mfma_f32_32x32x16_bf16(pf0, v00, oacc0, 0, 0, 0);
            oacc0 = __builtin_amdgcn_mfma_f32_32x32x16_bf16(pf1, v01, oacc0, 0, 0, 0);
            oacc1 = __builtin_amdgcn_mfma_f32_32x32x16_bf16(pf0, v10, oacc1, 0, 0, 0);
            oacc1 = __builtin_amdgcn_mfma_f32_32x32x16_bf16(pf1, v11, oacc1, 0, 0, 0);
            __builtin_amdgcn_s_setprio(0);
        }
    };

    // prologue: tile 0 -> buf0 (visible after first barrier); tile 1 -> regs
    load_regs(0);
    write_tile(Ks0, Vt0);
    load_regs(KTT);

    for (int kt = 0; kt < T; kt += 2 * KTT) {
        // tile kt from buf0; stage tile kt+KTT -> buf1; prefetch kt+2KTT
        half_iter(Ks0, Vt0, Ks1, Vt1, true,
                  (kt + 2 * KTT < T) ? kt + 2 * KTT : -1);
        // tile kt+KTT from buf1; stage kt+2KTT -> buf0; prefetch kt+3KTT
        half_iter(Ks1, Vt1, Ks0, Vt0, kt + 2 * KTT < T,
                  (kt + 3 * KTT < T) ? kt + 3 * KTT : -1);
    }

    // oacc: O[q][d], lane holds col d = dblk*32 + (lane&31),
    // reg r -> q-row (r&3) + 8*(r>>2) + 4*hi. lacc reg r -> l[same q]. ----
    #pragma unroll
    for (int r = 0; r < 16; ++r) {
        float inv = 1.0f / lacc[r];
        int row = (r & 3) + 8 * (r >> 2) + 4 * hi;
        short* op = O + (size_t)(b * T + qw + row) * C + h * Dh + r31;
        op[0]  = f2bf(oacc0[r] * inv);
        op[32] = f2bf(oacc1[r] * inv);
    }
}

// ---------------------------------------------------------------------------
// Launch
// ---------------------------------------------------------------------------
extern "C" void kernel_launch(void* const* d_in, const int* in_sizes, int n_in,
                              void* d_out, int out_size, void* d_ws, size_t ws_size,
                              hipStream_t stream) {
    (void)in_sizes; (void)n_in; (void)out_size; (void)ws_size;

    const float* x  = (const float*)d_in[0];
    const float* Wq = (const float*)d_in[1];
    const float* bq = (const float*)d_in[2];
    const float* Wk = (const float*)d_in[3];
    const float* bk = (const float*)d_in[4];
    const float* Wv = (const float*)d_in[5];
    const float* bv = (const float*)d_in[6];
    const float* Wp = (const float*)d_in[7];
    float* out = (float*)d_out;

    short* xb    = (short*)d_ws;                 // [M][C]      bf16
    short* Wqkv  = xb + (size_t)M * C;           // [2304][768] bf16
    short* Wpb   = Wqkv + 3 * (size_t)WS2;       // [768][768]  bf16
    short* QKVb  = Wpb + (size_t)WS2;            // [M][2304]   bf16 (Q pre-scaled)
    short* AOb   = QKVb + (size_t)M * NQKV;      // [M][C]      bf16

    convert_all<<<dim3(CV_TOTAL / 1024), 256, 0, stream>>>(
        x, Wq, Wk, Wv, Wp, xb, Wqkv, Wpb);

    // Fused QKV projection: [8192 x 2304], 128^2 tiles (r11-verified).
    gemm_bt<128, 2, 2, 1, 1><<<dim3(MTILES * (NQKV / 128)), 256, 0, stream>>>(
        xb, Wqkv, bq, bk, bv, QKVb, NQKV, C);

    // attn: 1-D grid 768, XCD-grouped (8 x 6 x 16), 256 threads
    attn_fwd<<<dim3((T / QT) * H * B), 256, 0, stream>>>(QKVb, AOb);

    // Output projection: [8192 x 768] fp32 out, BN=64 (r6-verified best).
    gemm_bt<64, 4, 1, 0, 0><<<dim3(MTILES * (C / 64)), 256, 0, stream>>>(
        AOb, Wpb, nullptr, nullptr, nullptr, out, C, C);
}